// Round 3
// baseline (883.341 us; speedup 1.0000x reference)
//
#include <hip/hip_runtime.h>

constexpr int F_IN  = 512;
constexpr int HID   = 16;
constexpr int NCLS  = 40;
constexpr int CHUNK = 4096;   // edges per count/scatter block
constexpr int BMAX  = 800;    // max buckets (N=100000 -> NB=782)

// ---- Pass A: per-chunk histogram of dst buckets (LDS atomics only) ----
__global__ void k_count(const int* __restrict__ dst, int* __restrict__ counts,
                        int E, int NB, int NBLKp) {
  __shared__ int hist[BMAX];
  int t = threadIdx.x;
  for (int b = t; b < BMAX; b += 256) hist[b] = 0;
  __syncthreads();
  int base = blockIdx.x * CHUNK;
  for (int i = 0; i < CHUNK; i += 256) {
    int e = base + i + t;
    if (e < E) atomicAdd(&hist[dst[e] >> 7], 1);
  }
  __syncthreads();
  for (int b = t; b < NB; b += 256) counts[b * NBLKp + blockIdx.x] = hist[b];
}

// ---- scan over counts (bucket-major), 3 stages, in-place ----
__global__ void k_scanA(const int* __restrict__ a, int* __restrict__ bsum) {
  __shared__ int sd[256];
  int t = threadIdx.x;
  int4 v = reinterpret_cast<const int4*>(a)[blockIdx.x * 256 + t];
  sd[t] = v.x + v.y + v.z + v.w;
  __syncthreads();
  for (int off = 128; off > 0; off >>= 1) {
    if (t < off) sd[t] += sd[t + off];
    __syncthreads();
  }
  if (!t) bsum[blockIdx.x] = sd[0];
}

__global__ void k_scanB(int* __restrict__ bsum, int nb) {
  __shared__ int sd[1024];
  int t = threadIdx.x;
  int v = (t < nb) ? bsum[t] : 0;
  sd[t] = v;
  __syncthreads();
  for (int off = 1; off < 1024; off <<= 1) {
    int add = (t >= off) ? sd[t - off] : 0;
    __syncthreads();
    sd[t] += add;
    __syncthreads();
  }
  if (t < nb) bsum[t] = sd[t] - v;  // exclusive
}

__global__ void k_scanC(int* __restrict__ a, const int* __restrict__ bsum) {
  __shared__ int sd[256];
  int t = threadIdx.x;
  int4 v = reinterpret_cast<int4*>(a)[blockIdx.x * 256 + t];
  int ts = v.x + v.y + v.z + v.w;
  sd[t] = ts;
  __syncthreads();
  for (int off = 1; off < 256; off <<= 1) {
    int add = (t >= off) ? sd[t - off] : 0;
    __syncthreads();
    sd[t] += add;
    __syncthreads();
  }
  int pre = bsum[blockIdx.x] + sd[t] - ts;
  int4 w;
  w.x = pre; w.y = pre + v.x; w.z = w.y + v.y; w.w = w.z + v.z;
  reinterpret_cast<int4*>(a)[blockIdx.x * 256 + t] = w;
}

// ---- Pass B: scatter edges into bucket-sorted payload (LDS cursors only) ----
__global__ void k_scatter(const int* __restrict__ src, const int* __restrict__ dst,
                          const float* __restrict__ ew, const int* __restrict__ counts,
                          uint2* __restrict__ payload, int E, int NB, int NBLKp) {
  __shared__ int cur[BMAX];
  int t = threadIdx.x;
  for (int b = t; b < NB; b += 256) cur[b] = counts[b * NBLKp + blockIdx.x];
  __syncthreads();
  int base = blockIdx.x * CHUNK;
  for (int i = 0; i < CHUNK; i += 256) {
    int e = base + i + t;
    if (e < E) {
      int s = src[e], d = dst[e];
      float w = ew[e];
      int pos = atomicAdd(&cur[d >> 7], 1);
      payload[pos] = make_uint2(((unsigned)s << 7) | (unsigned)(d & 127),
                                __float_as_uint(w));
    }
  }
}

// ---- per-bucket degree -> dis = rsqrt(1 + sum ew) ----
__global__ void k_degb(const uint2* __restrict__ payload, const int* __restrict__ counts,
                       float* __restrict__ dis, int N, int NBLKp) {
  __shared__ float dg[128];
  int t = threadIdx.x;
  if (t < 128) dg[t] = 1.0f;  // self-loop weight
  __syncthreads();
  int beg = counts[blockIdx.x * NBLKp], end = counts[(blockIdx.x + 1) * NBLKp];
  for (int e = beg + t; e < end; e += 256) {
    uint2 p = payload[e];
    atomicAdd(&dg[p.x & 127], __uint_as_float(p.y));
  }
  __syncthreads();
  int n = blockIdx.x * 128 + t;
  if (t < 128 && n < N) dis[n] = rsqrtf(dg[t]);
}

// ---- h1' = (x @ W1) * dis[n] ----
__global__ void k_gemm1(const float* __restrict__ x, const float* __restrict__ W1,
                        const float* __restrict__ dis, float* __restrict__ h1, int N) {
  int n = blockIdx.x * blockDim.x + threadIdx.x;
  if (n >= N) return;
  const float* xr = x + (size_t)n * F_IN;
  float acc[HID];
#pragma unroll
  for (int j = 0; j < HID; ++j) acc[j] = 0.0f;
  for (int k = 0; k < F_IN; k += 16) {
    float4 a0 = *reinterpret_cast<const float4*>(xr + k);
    float4 a1 = *reinterpret_cast<const float4*>(xr + k + 4);
    float4 a2 = *reinterpret_cast<const float4*>(xr + k + 8);
    float4 a3 = *reinterpret_cast<const float4*>(xr + k + 12);
    float xv[16] = {a0.x, a0.y, a0.z, a0.w, a1.x, a1.y, a1.z, a1.w,
                    a2.x, a2.y, a2.z, a2.w, a3.x, a3.y, a3.z, a3.w};
#pragma unroll
    for (int kk = 0; kk < 16; ++kk) {
      float xx = xv[kk];
      const float* wr = W1 + (size_t)(k + kk) * HID;
#pragma unroll
      for (int j = 0; j < HID; ++j) acc[j] = fmaf(xx, wr[j], acc[j]);
    }
  }
  float di = dis[n];
  float* hr = h1 + (size_t)n * HID;
#pragma unroll
  for (int j = 0; j < HID; ++j) hr[j] = acc[j] * di;
}

// ---- per-bucket aggregation; LAYER1: h2' = relu((acc+h')*dis+b1)*dis
//      LAYER2: g = (acc+h')*dis, then fused 16->40 GEMM + log_softmax ----
template <int LAYER>
__global__ void k_aggb(const uint2* __restrict__ payload, const int* __restrict__ counts,
                       const float* __restrict__ h, const float* __restrict__ dis,
                       const float* __restrict__ b1, const float* __restrict__ W2,
                       const float* __restrict__ b2, float* __restrict__ outp,
                       int N, int NBLKp) {
  __shared__ float acc[128 * HID];
  __shared__ float gT[(LAYER == 2) ? HID * 129 : 1];
  __shared__ float w2s[(LAYER == 2) ? HID * NCLS : 1];
  __shared__ float b2s[(LAYER == 2) ? NCLS : 1];
  int t = threadIdx.x;
  for (int i = t; i < 128 * HID; i += 256) acc[i] = 0.0f;
  if (LAYER == 2) {
    for (int i = t; i < HID * NCLS; i += 256) w2s[i] = W2[i];
    if (t < NCLS) b2s[t] = b2[t];
  }
  __syncthreads();
  int beg = counts[blockIdx.x * NBLKp], end = counts[(blockIdx.x + 1) * NBLKp];
  int j = t & 15;
  for (int e = beg + (t >> 4); e < end; e += 16) {
    uint2 p = payload[e];
    int s = (int)(p.x >> 7), dl = (int)(p.x & 127);
    atomicAdd(&acc[dl * HID + j], h[(size_t)s * HID + j] * __uint_as_float(p.y));
  }
  __syncthreads();
  int base = blockIdx.x * 128;
  if (LAYER == 1) {
    for (int i = t; i < 128 * HID; i += 256) {
      int n = base + (i >> 4);
      if (n < N) {
        int jj = i & 15;
        float di = dis[n];
        float v = (acc[i] + h[(size_t)n * HID + jj]) * di + b1[jj];
        outp[(size_t)n * HID + jj] = fmaxf(v, 0.0f) * di;
      }
    }
  } else {
    for (int i = t; i < 128 * HID; i += 256) {
      int nl = i >> 4, jj = i & 15;
      int n = base + nl;
      float g = 0.0f;
      if (n < N) g = (acc[i] + h[(size_t)n * HID + jj]) * dis[n];
      gT[jj * 129 + nl] = g;
    }
    __syncthreads();
    if (t < 128) {
      int n = base + t;
      if (n < N) {
        float o[NCLS];
#pragma unroll
        for (int c = 0; c < NCLS; ++c) o[c] = b2s[c];
#pragma unroll
        for (int k = 0; k < HID; ++k) {
          float gk = gT[k * 129 + t];
#pragma unroll
          for (int c = 0; c < NCLS; ++c) o[c] = fmaf(gk, w2s[k * NCLS + c], o[c]);
        }
        float m = o[0];
#pragma unroll
        for (int c = 1; c < NCLS; ++c) m = fmaxf(m, o[c]);
        float ss = 0.0f;
#pragma unroll
        for (int c = 0; c < NCLS; ++c) ss += expf(o[c] - m);
        float lse = m + logf(ss);
        float* orow = outp + (size_t)n * NCLS;
#pragma unroll
        for (int c = 0; c < NCLS / 2; ++c)
          reinterpret_cast<float2*>(orow)[c] = make_float2(o[2 * c] - lse, o[2 * c + 1] - lse);
      }
    }
  }
}

extern "C" void kernel_launch(void* const* d_in, const int* in_sizes, int n_in,
                              void* d_out, int out_size, void* d_ws, size_t ws_size,
                              hipStream_t stream) {
  const float* x  = (const float*)d_in[0];
  const int*   ei = (const int*)d_in[1];
  const float* ew = (const float*)d_in[2];
  const float* W1 = (const float*)d_in[3];
  const float* b1 = (const float*)d_in[4];
  const float* W2 = (const float*)d_in[5];
  const float* b2 = (const float*)d_in[6];
  float* out = (float*)d_out;

  const int N = in_sizes[0] / F_IN;   // 100000
  const int E = in_sizes[2];          // 3200000
  const int* src = ei;
  const int* dst = ei + E;

  const int NB    = (N + 127) >> 7;            // 782 buckets (<= BMAX)
  const int NBLK  = (E + CHUNK - 1) / CHUNK;   // 782 chunks
  const int NBLKp = (NBLK + 31) & ~31;         // 800
  const long long SCT = (long long)NB * NBLKp + 1;
  const int Npad  = (int)((SCT + 1023) & ~1023LL);
  const int nbScan = Npad / 1024;              // 612 (<= 1024)

  // ws layout (4B words): counts[Npad] | bsum[1024] | dis[Nround] | h1[N*16] | h2[N*16] | payload[2*E]
  int* counts = (int*)d_ws;
  int* bsum   = counts + Npad;
  float* dis  = (float*)(bsum + 1024);
  float* h1   = dis + ((N + 255) & ~255);
  float* h2   = h1 + (size_t)N * HID;
  uint2* payload = (uint2*)(h2 + (size_t)N * HID);

  hipMemsetAsync(counts, 0, (size_t)Npad * sizeof(int), stream);
  k_count<<<NBLK, 256, 0, stream>>>(dst, counts, E, NB, NBLKp);
  k_scanA<<<nbScan, 256, 0, stream>>>(counts, bsum);
  k_scanB<<<1, 1024, 0, stream>>>(bsum, nbScan);
  k_scanC<<<nbScan, 256, 0, stream>>>(counts, bsum);
  k_scatter<<<NBLK, 256, 0, stream>>>(src, dst, ew, counts, payload, E, NB, NBLKp);
  k_degb<<<NB, 256, 0, stream>>>(payload, counts, dis, N, NBLKp);
  k_gemm1<<<(N + 255) / 256, 256, 0, stream>>>(x, W1, dis, h1, N);
  k_aggb<1><<<NB, 256, 0, stream>>>(payload, counts, h1, dis, b1, nullptr, nullptr, h2, N, NBLKp);
  k_aggb<2><<<NB, 256, 0, stream>>>(payload, counts, h2, dis, nullptr, W2, b2, out, N, NBLKp);
}